// Round 1
// baseline (5317.931 us; speedup 1.0000x reference)
//
#include <hip/hip_runtime.h>
#include <stdint.h>

// ---------------- problem constants ----------------
constexpr int   WSZ   = 7;
constexpr int   NN    = 49;          // tokens per window
constexpr int   NHEAD = 3;
constexpr int   DIMC  = 96;
constexpr int   HDIM  = 32;
constexpr int   HHH   = 224;
constexpr int   NWIN  = 32;          // windows per side
constexpr int   LTOK  = HHH * HHH;   // 50176 tokens per batch image
constexpr int   BATCH = 16;
constexpr int   SHIFT = 3;
constexpr float QSCALE = 0.17677669529663687f;   // 32^-0.5
constexpr size_t YCOUNT = (size_t)BATCH * LTOK * DIMC;   // 77,070,336 floats

// ---------------- bf16 helpers ----------------
__device__ __forceinline__ float bf2f(unsigned short u) {
    union { unsigned int i; float f; } c; c.i = ((unsigned int)u) << 16; return c.f;
}
__device__ __forceinline__ unsigned short f2bf(float f) {
    union { float f; unsigned int i; } c; c.f = f;
    unsigned int r = c.i + 0x7fffu + ((c.i >> 16) & 1u);   // round-to-nearest-even
    return (unsigned short)(r >> 16);
}

// MFMA fragment types (gfx950: bf16 builtins take <8 x bfloat>)
typedef __bf16 bf16x8 __attribute__((ext_vector_type(8)));
typedef float  f32x4  __attribute__((ext_vector_type(4)));

// ---------------- LDS layout for attention kernel ----------------
// (UNCHANGED from verified 8110us kernel)
constexpr int QKV_OFF  = 0;
constexpr int H_OFF    = 28624;
constexpr int ATT_OFF  = 48224;
constexpr int RPB_OFF  = 57840;
constexpr int LIDX_OFF = 59872;
constexpr int SMEM_SZ  = 60080;

__launch_bounds__(256, 2)
__global__ void attn_kernel(const float* __restrict__ x,
                            const float* __restrict__ w_qkv,
                            const float* __restrict__ b_qkv,
                            const float* __restrict__ w_proj,
                            const float* __restrict__ b_proj,
                            const float* __restrict__ rpb,
                            const float* __restrict__ g1,
                            const float* __restrict__ be1,
                            float* __restrict__ out)
{
    __shared__ __align__(16) char smem[SMEM_SZ];
    unsigned short* qkv = (unsigned short*)(smem + QKV_OFF);   // [49][292] bf16
    float*  h_s    = (float*)(smem + H_OFF);                   // [49][100]
    float*  attn_s = (float*)(smem + ATT_OFF);                 // [49][49]
    float*  rpb_s  = (float*)(smem + RPB_OFF);                 // [169][3]
    int*    lidx   = (int*)(smem + LIDX_OFF);                  // [49]

    const int tid = threadIdx.x;
    const int w   = blockIdx.x;
    const int b   = w >> 10;
    const int wr  = (w >> 5) & 31;
    const int wc  = w & 31;

    // ---- phase 0: token -> flat index map, stage rpb table ----
    if (tid < NN) {
        int r = tid / WSZ, c = tid % WSZ;
        int gy = (wr * WSZ + r + SHIFT) % HHH;
        int gx = (wc * WSZ + c + SHIFT) % HHH;
        lidx[tid] = gy * HHH + gx;
    }
    for (int i = tid; i < 169 * NHEAD; i += 256) rpb_s[i] = rpb[i];
    __syncthreads();

    // ---- phase 1: stage x tile (alias of qkv region) ----
    float* xt = (float*)(smem + QKV_OFF);   // [49][100]
    const float* xb = x + (size_t)b * LTOK * DIMC;
    for (int i = tid; i < NN * DIMC; i += 256) {
        int n = i / DIMC, cc = i % DIMC;
        xt[n * 100 + cc] = xb[(size_t)lidx[n] * DIMC + cc];
    }
    __syncthreads();

    // ---- phase 2: LN1 (one thread per token) ----
    if (tid < NN) {
        float s = 0.f, ss = 0.f;
        for (int k = 0; k < DIMC; k++) { float v = xt[tid * 100 + k]; s += v; ss += v * v; }
        float mu  = s * (1.f / 96.f);
        float var = ss * (1.f / 96.f) - mu * mu;
        float inv = rsqrtf(var + 1e-5f);
        for (int k = 0; k < DIMC; k++) {
            float v = (xt[tid * 100 + k] - mu) * inv;
            h_s[tid * 100 + k] = v * g1[k] + be1[k];
        }
    }
    __syncthreads();

    // ---- phase 3: QKV projection, register-tiled (thread j owns column j) ----
    for (int jj = 0; jj < 3 * DIMC; jj += 256) {
        int j = jj + tid;
        if (j < 3 * DIMC) {
            float acc[NN];
            float bj = b_qkv[j];
#pragma unroll
            for (int t = 0; t < NN; t++) acc[t] = bj;
            for (int k4 = 0; k4 < DIMC; k4 += 4) {
                float w0 = w_qkv[(k4 + 0) * 288 + j];
                float w1 = w_qkv[(k4 + 1) * 288 + j];
                float w2 = w_qkv[(k4 + 2) * 288 + j];
                float w3 = w_qkv[(k4 + 3) * 288 + j];
#pragma unroll
                for (int t = 0; t < NN; t++) {
                    const float4 hv = *(const float4*)&h_s[t * 100 + k4];
                    acc[t] = fmaf(hv.x, w0, acc[t]);
                    acc[t] = fmaf(hv.y, w1, acc[t]);
                    acc[t] = fmaf(hv.z, w2, acc[t]);
                    acc[t] = fmaf(hv.w, w3, acc[t]);
                }
            }
            float sc = (j < DIMC) ? QSCALE : 1.f;   // fold q*scale
#pragma unroll
            for (int t = 0; t < NN; t++) qkv[t * 292 + j] = f2bf(acc[t] * sc);
        }
    }
    __syncthreads();

    // ---- phase 4: per-head attention ----
    float* aout_s = (float*)(smem + H_OFF);   // attn-out accumulator [49][100]
    for (int h = 0; h < NHEAD; h++) {
        // 4a: logits = (q*scale) . k + bias
        for (int idx = tid; idx < NN * NN; idx += 256) {
            int n = idx / NN, m = idx % NN;
            const unsigned short* qr = &qkv[n * 292 + h * HDIM];
            const unsigned short* kr = &qkv[m * 292 + DIMC + h * HDIM];
            float acc = 0.f;
#pragma unroll
            for (int d4 = 0; d4 < HDIM; d4 += 4) {
                ushort4 qu = *(const ushort4*)&qr[d4];
                ushort4 ku = *(const ushort4*)&kr[d4];
                acc = fmaf(bf2f(qu.x), bf2f(ku.x), acc);
                acc = fmaf(bf2f(qu.y), bf2f(ku.y), acc);
                acc = fmaf(bf2f(qu.z), bf2f(ku.z), acc);
                acc = fmaf(bf2f(qu.w), bf2f(ku.w), acc);
            }
            int rn = n / WSZ, cn = n % WSZ, rm = m / WSZ, cm = m % WSZ;
            int rel = (rn - rm + 6) * 13 + (cn - cm + 6);
            attn_s[idx] = acc + rpb_s[rel * NHEAD + h];
        }
        __syncthreads();

        // 4b: softmax per row (one thread per row)
        if (tid < NN) {
            float mx = -1e30f;
            for (int m = 0; m < NN; m++) mx = fmaxf(mx, attn_s[tid * NN + m]);
            float s = 0.f;
            for (int m = 0; m < NN; m++) {
                float e = __expf(attn_s[tid * NN + m] - mx);
                attn_s[tid * NN + m] = e; s += e;
            }
            float inv = 1.f / s;
            for (int m = 0; m < NN; m++) attn_s[tid * NN + m] *= inv;
        }
        __syncthreads();

        // 4c: write probs to output (coalesced)
        float* ag = out + YCOUNT + ((size_t)w * NHEAD + h) * NN * NN;
        for (int idx = tid; idx < NN * NN; idx += 256) ag[idx] = attn_s[idx];

        // 4d: PV -> attn-out columns [h*32 .. h*32+31]
        for (int u = tid; u < NN * (HDIM / 4); u += 256) {    // 392 units
            int n = u / (HDIM / 4), d4 = (u % (HDIM / 4)) * 4;
            float a0 = 0.f, a1 = 0.f, a2 = 0.f, a3 = 0.f;
            for (int m = 0; m < NN; m++) {
                float p = attn_s[n * NN + m];
                ushort4 vu = *(const ushort4*)&qkv[m * 292 + 2 * DIMC + h * HDIM + d4];
                a0 = fmaf(p, bf2f(vu.x), a0);
                a1 = fmaf(p, bf2f(vu.y), a1);
                a2 = fmaf(p, bf2f(vu.z), a2);
                a3 = fmaf(p, bf2f(vu.w), a3);
            }
            *(float4*)&aout_s[n * 100 + h * HDIM + d4] = make_float4(a0, a1, a2, a3);
        }
        __syncthreads();
    }

    // ---- phase 5: stage w_proj^T (bf16) into qkv region (now dead) ----
    unsigned short* wp = (unsigned short*)(smem + QKV_OFF);   // [96][100], wp[c][k]
    for (int i = tid; i < DIMC * DIMC; i += 256) {
        int cc = i / DIMC, kk = i % DIMC;
        wp[cc * 100 + kk] = f2bf(w_proj[kk * DIMC + cc]);
    }
    __syncthreads();

    // ---- phase 6: proj + bias + residual, scatter back ----
    for (int idx = tid; idx < NN * DIMC; idx += 256) {
        int n = idx / DIMC, cc = idx % DIMC;
        float acc = b_proj[cc];
#pragma unroll
        for (int k4 = 0; k4 < DIMC; k4 += 4) {
            const float4 av = *(const float4*)&aout_s[n * 100 + k4];
            ushort4 wv = *(const ushort4*)&wp[cc * 100 + k4];
            acc = fmaf(av.x, bf2f(wv.x), acc);
            acc = fmaf(av.y, bf2f(wv.y), acc);
            acc = fmaf(av.z, bf2f(wv.z), acc);
            acc = fmaf(av.w, bf2f(wv.w), acc);
        }
        size_t gi = ((size_t)b * LTOK + lidx[n]) * DIMC + cc;
        out[gi] = x[gi] + acc;    // y1 = shortcut + attn branch
    }
}

// ---------------- weight prep: transpose+convert MLP weights to bf16 ----------------
// w1t[h][k] = wf1[k][h]   (384 x 96)  -- A-operand layout for fc1 (swapped)
// w2t[c][k] = wf2[k][c]   (96 x 384)  -- B-operand layout for fc2
__global__ void prep_weights(const float* __restrict__ wf1,
                             const float* __restrict__ wf2,
                             unsigned short* __restrict__ w1t,
                             unsigned short* __restrict__ w2t)
{
    int i = blockIdx.x * 256 + threadIdx.x;
    if (i < 384 * 96) {
        int h = i / 96, k = i % 96;
        w1t[i] = f2bf(wf1[k * 384 + h]);
        int c = i / 384, kk = i % 384;
        w2t[i] = f2bf(wf2[kk * 96 + c]);
    }
}

// ---------------- MLP kernel (MFMA bf16): y += fc2(gelu(fc1(LN2(y)))) ----------------
// 64 tokens per block, 4 waves (256 threads).
// fc1 computed with SWAPPED operands: D1[h][t] = W1T(A) x H^T(B) so each lane's
// D fragment holds 4 consecutive hidden values for one token -> single 8B LDS
// store into ms[t][k]-row-major, which is exactly fc2's A-fragment layout.
// MFMA conventions used (learn_hip m89/m97 verified):
//   A/B frag: non-K index = lane%16, k = (lane/16)*8 + i (8 contiguous bf16, 16B load)
//   C/D frag: col = lane&15, row = (lane>>4)*4 + reg
constexpr int MTOK = 64;                      // tokens per block
constexpr int H2_STRIDE = 104;                // bf16 elems/row (pad: 52 words %32=20 -> 2-way)
constexpr int MS_STRIDE = 392;                // bf16 elems/row (pad: 196 words %32=4 -> 2-way)

__launch_bounds__(256, 2)
__global__ void mlp_mfma_kernel(float* __restrict__ y,
                                const float* __restrict__ g2,
                                const float* __restrict__ be2,
                                const float* __restrict__ bf1,
                                const float* __restrict__ bf2v,
                                const unsigned short* __restrict__ w1t,
                                const unsigned short* __restrict__ w2t)
{
    __shared__ __align__(16) unsigned short h2s[MTOK * H2_STRIDE];   // 13,312 B  LN2 out (bf16)
    __shared__ __align__(16) unsigned short mss[MTOK * MS_STRIDE];   // 50,176 B  gelu(fc1) (bf16)

    const int tid  = threadIdx.x;
    const int wave = tid >> 6;
    const int lane = tid & 63;
    const int lm   = lane & 15;       // non-K fragment index
    const int lk   = lane >> 4;       // k-group
    const size_t t0 = (size_t)blockIdx.x * MTOK;

    // ---- LN2: 4 lanes per token, each owns 24 channels ----
    {
        const int token = tid >> 2;           // 0..63 (4 lanes/token, same wave)
        const int q     = tid & 3;
        const float* yrow = y + (t0 + token) * 96 + q * 24;
        float v[24];
#pragma unroll
        for (int j4 = 0; j4 < 24; j4 += 4) {
            float4 t = *(const float4*)(yrow + j4);
            v[j4] = t.x; v[j4 + 1] = t.y; v[j4 + 2] = t.z; v[j4 + 3] = t.w;
        }
        float s = 0.f, ss = 0.f;
#pragma unroll
        for (int j = 0; j < 24; j++) { s += v[j]; ss += v[j] * v[j]; }
        s  += __shfl_xor(s, 1);  s  += __shfl_xor(s, 2);
        ss += __shfl_xor(ss, 1); ss += __shfl_xor(ss, 2);
        float mu  = s * (1.f / 96.f);
        float var = ss * (1.f / 96.f) - mu * mu;
        float inv = rsqrtf(var + 1e-5f);
#pragma unroll
        for (int j4 = 0; j4 < 24; j4 += 4) {
            float4 gv = *(const float4*)&g2[q * 24 + j4];
            float4 bv = *(const float4*)&be2[q * 24 + j4];
            unsigned short b0 = f2bf((v[j4 + 0] - mu) * inv * gv.x + bv.x);
            unsigned short b1 = f2bf((v[j4 + 1] - mu) * inv * gv.y + bv.y);
            unsigned short b2 = f2bf((v[j4 + 2] - mu) * inv * gv.z + bv.z);
            unsigned short b3 = f2bf((v[j4 + 3] - mu) * inv * gv.w + bv.w);
            *(unsigned int*)&h2s[token * H2_STRIDE + q * 24 + j4]     = (unsigned)b0 | ((unsigned)b1 << 16);
            *(unsigned int*)&h2s[token * H2_STRIDE + q * 24 + j4 + 2] = (unsigned)b2 | ((unsigned)b3 << 16);
        }
    }
    __syncthreads();

    // ---- fc1 (swapped): wave owns 6 hidden m-tiles x 4 token n-tiles, K=96 ----
    {
        f32x4 acc[6][4];
#pragma unroll
        for (int mi = 0; mi < 6; mi++) {
            const float4 bv = *(const float4*)&bf1[(wave * 6 + mi) * 16 + lk * 4];
            f32x4 bi = {bv.x, bv.y, bv.z, bv.w};
#pragma unroll
            for (int n4 = 0; n4 < 4; n4++) acc[mi][n4] = bi;
        }
#pragma unroll
        for (int kt = 0; kt < 3; kt++) {
            bf16x8 bfrag[4];
#pragma unroll
            for (int n4 = 0; n4 < 4; n4++)
                bfrag[n4] = *(const bf16x8*)&h2s[(n4 * 16 + lm) * H2_STRIDE + kt * 32 + lk * 8];
            bf16x8 afrag[6];
#pragma unroll
            for (int mi = 0; mi < 6; mi++)
                afrag[mi] = *(const bf16x8*)&w1t[((wave * 6 + mi) * 16 + lm) * 96 + kt * 32 + lk * 8];
#pragma unroll
            for (int mi = 0; mi < 6; mi++)
#pragma unroll
                for (int n4 = 0; n4 < 4; n4++)
                    acc[mi][n4] = __builtin_amdgcn_mfma_f32_16x16x32_bf16(
                        afrag[mi], bfrag[n4], acc[mi][n4], 0, 0, 0);
        }
        // GELU + pack: lane holds 4 consecutive hidden for token t -> one 8B store
#pragma unroll
        for (int mi = 0; mi < 6; mi++) {
            const int h0 = (wave * 6 + mi) * 16 + lk * 4;
#pragma unroll
            for (int n4 = 0; n4 < 4; n4++) {
                const int t = n4 * 16 + lm;
                ushort4 pk;
#pragma unroll
                for (int r = 0; r < 4; r++) {
                    float vv = acc[mi][n4][r];
                    float gl = 0.5f * vv * (1.0f + erff(vv * 0.70710678118654752f));
                    ((unsigned short*)&pk)[r] = f2bf(gl);
                }
                *(ushort4*)&mss[t * MS_STRIDE + h0] = pk;
            }
        }
    }
    __syncthreads();

    // ---- fc2 + residual: wave owns 1 token m-tile x 6 out n-tiles, K=384 ----
    {
        f32x4 acc2[6];
#pragma unroll
        for (int nt = 0; nt < 6; nt++) {
            float bb = bf2v[nt * 16 + lm];
            acc2[nt] = {bb, bb, bb, bb};
        }
#pragma unroll 4
        for (int kt = 0; kt < 12; kt++) {
            bf16x8 a = *(const bf16x8*)&mss[(wave * 16 + lm) * MS_STRIDE + kt * 32 + lk * 8];
#pragma unroll
            for (int nt = 0; nt < 6; nt++) {
                bf16x8 bb = *(const bf16x8*)&w2t[(nt * 16 + lm) * 384 + kt * 32 + lk * 8];
                acc2[nt] = __builtin_amdgcn_mfma_f32_16x16x32_bf16(a, bb, acc2[nt], 0, 0, 0);
            }
        }
        // epilogue: D col = out-channel (lane&15), rows = 4 consecutive tokens
#pragma unroll
        for (int nt = 0; nt < 6; nt++) {
            const int c = nt * 16 + lm;
#pragma unroll
            for (int r = 0; r < 4; r++) {
                const int t = wave * 16 + lk * 4 + r;
                size_t gi = (t0 + t) * 96 + c;
                y[gi] = y[gi] + acc2[nt][r];
            }
        }
    }
}

// ---------------- launcher ----------------
extern "C" void kernel_launch(void* const* d_in, const int* in_sizes, int n_in,
                              void* d_out, int out_size, void* d_ws, size_t ws_size,
                              hipStream_t stream) {
    const float* x      = (const float*)d_in[0];
    const float* w_qkv  = (const float*)d_in[1];
    const float* b_qkv  = (const float*)d_in[2];
    const float* w_proj = (const float*)d_in[3];
    const float* b_proj = (const float*)d_in[4];
    const float* rpb    = (const float*)d_in[5];
    const float* g1     = (const float*)d_in[6];
    const float* be1    = (const float*)d_in[7];
    const float* g2     = (const float*)d_in[8];
    const float* be2    = (const float*)d_in[9];
    const float* wf1    = (const float*)d_in[10];
    const float* bf1    = (const float*)d_in[11];
    const float* wf2    = (const float*)d_in[12];
    const float* bf2v   = (const float*)d_in[13];
    float* out = (float*)d_out;

    // workspace: bf16 transposed MLP weights (2 x 73,728 B)
    unsigned short* w1t = (unsigned short*)d_ws;
    unsigned short* w2t = w1t + 384 * 96;

    prep_weights<<<144, 256, 0, stream>>>(wf1, wf2, w1t, w2t);

    const int nwin_total = BATCH * NWIN * NWIN;          // 16384
    attn_kernel<<<nwin_total, 256, 0, stream>>>(x, w_qkv, b_qkv, w_proj, b_proj,
                                                rpb, g1, be1, out);

    const int ntok_blocks = (BATCH * LTOK) / MTOK;       // 12544
    mlp_mfma_kernel<<<ntok_blocks, 256, 0, stream>>>(out, g2, be2, bf1, bf2v, w1t, w2t);
}

// Round 2
// 1998.395 us; speedup vs baseline: 2.6611x; 2.6611x over previous
//
#include <hip/hip_runtime.h>
#include <stdint.h>

// ---------------- problem constants ----------------
constexpr int   WSZ   = 7;
constexpr int   NN    = 49;          // tokens per window
constexpr int   NHEAD = 3;
constexpr int   DIMC  = 96;
constexpr int   HDIM  = 32;
constexpr int   HHH   = 224;
constexpr int   NWIN  = 32;          // windows per side
constexpr int   LTOK  = HHH * HHH;   // 50176 tokens per batch image
constexpr int   BATCH = 16;
constexpr int   SHIFT = 3;
constexpr float QSCALE = 0.17677669529663687f;   // 32^-0.5
constexpr size_t YCOUNT = (size_t)BATCH * LTOK * DIMC;   // 77,070,336 floats

// ---------------- bf16 helpers ----------------
__device__ __forceinline__ float bf2f(unsigned short u) {
    union { unsigned int i; float f; } c; c.i = ((unsigned int)u) << 16; return c.f;
}
__device__ __forceinline__ unsigned short f2bf(float f) {
    union { float f; unsigned int i; } c; c.f = f;
    unsigned int r = c.i + 0x7fffu + ((c.i >> 16) & 1u);   // round-to-nearest-even
    return (unsigned short)(r >> 16);
}

// MFMA fragment types
typedef __bf16 bf16x8 __attribute__((ext_vector_type(8)));
typedef float  f32x4  __attribute__((ext_vector_type(4)));

// =====================================================================
// MFMA attention kernel. One window (49 tokens -> padded 64) per block,
// 4 waves; wave mt owns token rows [mt*16, mt*16+16) through ALL phases,
// so only 2 __syncthreads are needed (after index staging, after QKV).
// MFMA conventions (learn_hip m89/m97 verified):
//   A-frag: lane holds A[lane%16][ (lane/16)*8 + i ]  (8 contiguous k, 16B)
//   B-frag: lane holds B[ (lane/16)*8 + i ][lane%16 ]  (i.e. B^T row-major)
//   C/D:    col = lane&15, row = (lane>>4)*4 + reg
// ---------------------------------------------------------------------
// LDS layout (bytes):
constexpr int QK_STR = 200;   // q|k row stride (elems): 100 words -> 8 banks
constexpr int VT_STR = 72;    // vT row stride
constexpr int H_STR  = 104;   // h / aout row stride
constexpr int P_STR  = 72;    // p row stride
constexpr int QK_OFF  = 0;        // ushort [64][200]  q cols 0..95, k cols 96..191
constexpr int VT_OFF  = 25600;    // ushort [96][72]   v transposed [d][token]
constexpr int HA_OFF  = 39424;    // ushort [64][104]  h (LN1 out); aliased by aout after QKV
constexpr int P_OFF   = 52736;    // ushort [64][72]   softmax probs bf16
constexpr int RPB_OFF = 61952;    // float  [169*3]
constexpr int LIDX_OFF= 63980;    // int    [49]
constexpr int RC_OFF  = 64176;    // int    [64]  (r7<<8)|c7, 0 for n>=49
constexpr int SMEM2   = 64432;

__launch_bounds__(256, 2)
__global__ void attn_mfma_kernel(const float* __restrict__ x,
                                 const float* __restrict__ rpb,
                                 const float* __restrict__ g1,
                                 const float* __restrict__ be1,
                                 const float* __restrict__ b_proj,
                                 const unsigned short* __restrict__ wqkvT,
                                 const unsigned short* __restrict__ wprojT,
                                 const float* __restrict__ bqkv,
                                 float* __restrict__ out)
{
    __shared__ __align__(16) char smem[SMEM2];
    unsigned short* qk_s  = (unsigned short*)(smem + QK_OFF);
    unsigned short* vT_s  = (unsigned short*)(smem + VT_OFF);
    unsigned short* h_s   = (unsigned short*)(smem + HA_OFF);
    unsigned short* aout_s= (unsigned short*)(smem + HA_OFF);   // alias (h dead after QKV)
    unsigned short* p_s   = (unsigned short*)(smem + P_OFF);
    float* rpb_s = (float*)(smem + RPB_OFF);
    int*   lidx  = (int*)(smem + LIDX_OFF);
    int*   rc7   = (int*)(smem + RC_OFF);

    const int tid  = threadIdx.x;
    const int wave = tid >> 6;
    const int lane = tid & 63;
    const int lm   = lane & 15;
    const int lk   = lane >> 4;
    const int row0 = wave * 16;          // wave's token-tile base

    const int w  = blockIdx.x;
    const int b  = w >> 10;
    const int wr = (w >> 5) & 31;
    const int wc = w & 31;

    // ---- phase 0: index maps + rpb staging ----
    if (tid < 64) {
        if (tid < NN) {
            int r = tid / WSZ, c = tid % WSZ;
            int gy = (wr * WSZ + r + SHIFT) % HHH;
            int gx = (wc * WSZ + c + SHIFT) % HHH;
            lidx[tid] = gy * HHH + gx;
            rc7[tid] = (r << 8) | c;
        } else {
            rc7[tid] = 0;
        }
    }
    for (int i = tid; i < 169 * NHEAD; i += 256) rpb_s[i] = rpb[i];
    __syncthreads();

    // ---- phase 1: LN1 straight from global -> h bf16 (4 lanes per token) ----
    {
        const int t = tid >> 2, q = tid & 3;
        if (t < NN) {
            const float* xrow = x + ((size_t)b * LTOK + lidx[t]) * DIMC + q * 24;
            float v[24];
#pragma unroll
            for (int j4 = 0; j4 < 24; j4 += 4) {
                float4 tv = *(const float4*)(xrow + j4);
                v[j4] = tv.x; v[j4+1] = tv.y; v[j4+2] = tv.z; v[j4+3] = tv.w;
            }
            float s = 0.f, ss = 0.f;
#pragma unroll
            for (int j = 0; j < 24; j++) { s += v[j]; ss += v[j] * v[j]; }
            s  += __shfl_xor(s, 1);  s  += __shfl_xor(s, 2);
            ss += __shfl_xor(ss, 1); ss += __shfl_xor(ss, 2);
            float mu  = s * (1.f / 96.f);
            float var = ss * (1.f / 96.f) - mu * mu;
            float inv = rsqrtf(var + 1e-5f);
#pragma unroll
            for (int j4 = 0; j4 < 24; j4 += 2) {
                float2 gv = *(const float2*)&g1[q * 24 + j4];
                float2 bv = *(const float2*)&be1[q * 24 + j4];
                unsigned short b0 = f2bf((v[j4+0] - mu) * inv * gv.x + bv.x);
                unsigned short b1 = f2bf((v[j4+1] - mu) * inv * gv.y + bv.y);
                *(unsigned int*)&h_s[t * H_STR + q * 24 + j4] = (unsigned)b0 | ((unsigned)b1 << 16);
            }
        } else {
            // zero pad rows so v-padding stays finite
#pragma unroll
            for (int j4 = 0; j4 < 24; j4 += 2)
                *(unsigned int*)&h_s[t * H_STR + q * 24 + j4] = 0u;
        }
    }
    // wave reads only its own h rows below -> no barrier needed here

    // ---- phase 2: QKV projection (MFMA), K=96, 18 N-tiles ----
    {
        bf16x8 aq[3];
#pragma unroll
        for (int kt = 0; kt < 3; kt++)
            aq[kt] = *(const bf16x8*)&h_s[(row0 + lm) * H_STR + kt * 32 + lk * 8];
#pragma unroll 3
        for (int jt = 0; jt < 18; jt++) {
            float bb = bqkv[jt * 16 + lm];
            f32x4 acc = {bb, bb, bb, bb};
#pragma unroll
            for (int kt = 0; kt < 3; kt++) {
                bf16x8 bw = *(const bf16x8*)&wqkvT[(jt * 16 + lm) * 96 + kt * 32 + lk * 8];
                acc = __builtin_amdgcn_mfma_f32_16x16x32_bf16(aq[kt], bw, acc, 0, 0, 0);
            }
            if (jt < 12) {            // q (0..95) and k (96..191) -> qk_s rows
                int col = jt * 16 + lm;
#pragma unroll
                for (int r = 0; r < 4; r++)
                    qk_s[(row0 + lk * 4 + r) * QK_STR + col] = f2bf(acc[r]);
            } else {                  // v -> transposed vT[d][token], 8B store
                int d = (jt - 12) * 16 + lm;
                ushort4 pk;
#pragma unroll
                for (int r = 0; r < 4; r++) ((unsigned short*)&pk)[r] = f2bf(acc[r]);
                *(ushort4*)&vT_s[d * VT_STR + row0 + lk * 4] = pk;
            }
        }
    }
    __syncthreads();   // k rows / v cols are read cross-wave below

    // ---- precompute rel-bias indices (16 per lane) ----
    int rel[4][4];
#pragma unroll
    for (int r = 0; r < 4; r++) {
        int n = row0 + lk * 4 + r;
        int rcn = rc7[n];
        int rn = rcn >> 8, cn = rcn & 255;
#pragma unroll
        for (int nt = 0; nt < 4; nt++) {
            int m = nt * 16 + lm;
            int rcm = rc7[m];
            int rm = rcm >> 8, cm = rcm & 255;
            rel[r][nt] = (rn - rm + 6) * 13 + (cn - cm + 6);
        }
    }

    // ---- phase 3: per-head attention (no barriers: wave-private rows) ----
    for (int h = 0; h < NHEAD; h++) {
        // 3a: logits = q . k^T  (scale pre-folded into q weights)
        bf16x8 afq = *(const bf16x8*)&qk_s[(row0 + lm) * QK_STR + h * HDIM + lk * 8];
        f32x4 lg[4];
#pragma unroll
        for (int nt = 0; nt < 4; nt++) {
            bf16x8 bk = *(const bf16x8*)&qk_s[(nt * 16 + lm) * QK_STR + 96 + h * HDIM + lk * 8];
            f32x4 z = {0.f, 0.f, 0.f, 0.f};
            lg[nt] = __builtin_amdgcn_mfma_f32_16x16x32_bf16(afq, bk, z, 0, 0, 0);
        }
        // 3b: bias + mask + in-register softmax (row n lives in 16 lanes)
        float pv[4][4];
#pragma unroll
        for (int r = 0; r < 4; r++)
#pragma unroll
            for (int nt = 0; nt < 4; nt++) {
                int m = nt * 16 + lm;
                float v = lg[nt][r] + rpb_s[rel[r][nt] * 3 + h];
                pv[r][nt] = (m < NN) ? v : -1e30f;
            }
        float mx[4], sm[4];
#pragma unroll
        for (int r = 0; r < 4; r++)
            mx[r] = fmaxf(fmaxf(pv[r][0], pv[r][1]), fmaxf(pv[r][2], pv[r][3]));
#pragma unroll
        for (int st = 1; st <= 8; st <<= 1)
#pragma unroll
            for (int r = 0; r < 4; r++) mx[r] = fmaxf(mx[r], __shfl_xor(mx[r], st));
#pragma unroll
        for (int r = 0; r < 4; r++) {
            sm[r] = 0.f;
#pragma unroll
            for (int nt = 0; nt < 4; nt++) {
                float e = __expf(pv[r][nt] - mx[r]);
                pv[r][nt] = e; sm[r] += e;
            }
        }
#pragma unroll
        for (int st = 1; st <= 8; st <<= 1)
#pragma unroll
            for (int r = 0; r < 4; r++) sm[r] += __shfl_xor(sm[r], st);

        // 3c: normalize; write probs to global + bf16 p to LDS
        float* ag = out + YCOUNT + ((size_t)w * NHEAD + h) * (NN * NN);
#pragma unroll
        for (int r = 0; r < 4; r++) {
            float inv = 1.f / sm[r];
            int n = row0 + lk * 4 + r;
#pragma unroll
            for (int nt = 0; nt < 4; nt++) {
                float p = pv[r][nt] * inv;
                int m = nt * 16 + lm;
                p_s[n * P_STR + m] = f2bf(p);          // 0 where masked -> K-padding
                if (n < NN && m < NN) ag[n * NN + m] = p;
            }
        }

        // 3d: PV (K=64) -> aout columns [h*32, h*32+32)
        bf16x8 ap0 = *(const bf16x8*)&p_s[(row0 + lm) * P_STR + lk * 8];
        bf16x8 ap1 = *(const bf16x8*)&p_s[(row0 + lm) * P_STR + 32 + lk * 8];
        f32x4 opv[2];
#pragma unroll
        for (int nt = 0; nt < 2; nt++) {
            f32x4 z = {0.f, 0.f, 0.f, 0.f};
            bf16x8 bv0 = *(const bf16x8*)&vT_s[(h * HDIM + nt * 16 + lm) * VT_STR + lk * 8];
            bf16x8 bv1 = *(const bf16x8*)&vT_s[(h * HDIM + nt * 16 + lm) * VT_STR + 32 + lk * 8];
            z = __builtin_amdgcn_mfma_f32_16x16x32_bf16(ap0, bv0, z, 0, 0, 0);
            z = __builtin_amdgcn_mfma_f32_16x16x32_bf16(ap1, bv1, z, 0, 0, 0);
            opv[nt] = z;
        }
#pragma unroll
        for (int nt = 0; nt < 2; nt++)
#pragma unroll
            for (int r = 0; r < 4; r++)
                aout_s[(row0 + lk * 4 + r) * H_STR + h * HDIM + nt * 16 + lm] = f2bf(opv[nt][r]);
    }

    // ---- phase 4: proj (K=96) + bias + residual scatter ----
    {
        bf16x8 aa[3];
#pragma unroll
        for (int kt = 0; kt < 3; kt++)
            aa[kt] = *(const bf16x8*)&aout_s[(row0 + lm) * H_STR + kt * 32 + lk * 8];
        f32x4 acc[6];
#pragma unroll
        for (int ntc = 0; ntc < 6; ntc++) {
            float bb = b_proj[ntc * 16 + lm];
            f32x4 a = {bb, bb, bb, bb};
#pragma unroll
            for (int kt = 0; kt < 3; kt++) {
                bf16x8 bw = *(const bf16x8*)&wprojT[(ntc * 16 + lm) * 96 + kt * 32 + lk * 8];
                a = __builtin_amdgcn_mfma_f32_16x16x32_bf16(aa[kt], bw, a, 0, 0, 0);
            }
            acc[ntc] = a;
        }
#pragma unroll
        for (int r = 0; r < 4; r++) {
            int n = row0 + lk * 4 + r;
            if (n < NN) {
                size_t grow = ((size_t)b * LTOK + lidx[n]) * DIMC;
#pragma unroll
                for (int ntc = 0; ntc < 6; ntc++) {
                    size_t gi = grow + ntc * 16 + lm;
                    out[gi] = x[gi] + acc[ntc][r];
                }
            }
        }
    }
}

// ---------------- weight prep: transpose+convert to bf16 ----------------
__global__ void prep_weights(const float* __restrict__ wf1,
                             const float* __restrict__ wf2,
                             const float* __restrict__ wqkv,
                             const float* __restrict__ bqkv_in,
                             const float* __restrict__ wproj,
                             unsigned short* __restrict__ w1t,
                             unsigned short* __restrict__ w2t,
                             unsigned short* __restrict__ wqkvT,
                             unsigned short* __restrict__ wprojT,
                             float* __restrict__ bqkv_out)
{
    int i = blockIdx.x * 256 + threadIdx.x;
    if (i < 384 * 96) {
        int h = i / 96, k = i % 96;
        w1t[i] = f2bf(wf1[k * 384 + h]);
        int c = i / 384, kk = i % 384;
        w2t[i] = f2bf(wf2[kk * 96 + c]);
    }
    if (i < 288 * 96) {                       // wqkvT[j][k], q-scale folded
        int j = i / 96, k = i % 96;
        float s = (j < DIMC) ? QSCALE : 1.f;
        wqkvT[i] = f2bf(wqkv[k * 288 + j] * s);
    }
    if (i < 96 * 96) {                        // wprojT[c][k]
        int c = i / 96, k = i % 96;
        wprojT[i] = f2bf(wproj[k * 96 + c]);
    }
    if (i < 288) bqkv_out[i] = bqkv_in[i] * ((i < DIMC) ? QSCALE : 1.f);
}

// ---------------- MLP kernel (MFMA bf16, verified r1): y += fc2(gelu(fc1(LN2(y)))) ----------------
constexpr int MTOK = 64;
constexpr int H2_STRIDE = 104;
constexpr int MS_STRIDE = 392;

__launch_bounds__(256, 2)
__global__ void mlp_mfma_kernel(float* __restrict__ y,
                                const float* __restrict__ g2,
                                const float* __restrict__ be2,
                                const float* __restrict__ bf1,
                                const float* __restrict__ bf2v,
                                const unsigned short* __restrict__ w1t,
                                const unsigned short* __restrict__ w2t)
{
    __shared__ __align__(16) unsigned short h2s[MTOK * H2_STRIDE];
    __shared__ __align__(16) unsigned short mss[MTOK * MS_STRIDE];

    const int tid  = threadIdx.x;
    const int wave = tid >> 6;
    const int lane = tid & 63;
    const int lm   = lane & 15;
    const int lk   = lane >> 4;
    const size_t t0 = (size_t)blockIdx.x * MTOK;

    {
        const int token = tid >> 2;
        const int q     = tid & 3;
        const float* yrow = y + (t0 + token) * 96 + q * 24;
        float v[24];
#pragma unroll
        for (int j4 = 0; j4 < 24; j4 += 4) {
            float4 t = *(const float4*)(yrow + j4);
            v[j4] = t.x; v[j4 + 1] = t.y; v[j4 + 2] = t.z; v[j4 + 3] = t.w;
        }
        float s = 0.f, ss = 0.f;
#pragma unroll
        for (int j = 0; j < 24; j++) { s += v[j]; ss += v[j] * v[j]; }
        s  += __shfl_xor(s, 1);  s  += __shfl_xor(s, 2);
        ss += __shfl_xor(ss, 1); ss += __shfl_xor(ss, 2);
        float mu  = s * (1.f / 96.f);
        float var = ss * (1.f / 96.f) - mu * mu;
        float inv = rsqrtf(var + 1e-5f);
#pragma unroll
        for (int j4 = 0; j4 < 24; j4 += 4) {
            float4 gv = *(const float4*)&g2[q * 24 + j4];
            float4 bv = *(const float4*)&be2[q * 24 + j4];
            unsigned short b0 = f2bf((v[j4 + 0] - mu) * inv * gv.x + bv.x);
            unsigned short b1 = f2bf((v[j4 + 1] - mu) * inv * gv.y + bv.y);
            unsigned short b2 = f2bf((v[j4 + 2] - mu) * inv * gv.z + bv.z);
            unsigned short b3 = f2bf((v[j4 + 3] - mu) * inv * gv.w + bv.w);
            *(unsigned int*)&h2s[token * H2_STRIDE + q * 24 + j4]     = (unsigned)b0 | ((unsigned)b1 << 16);
            *(unsigned int*)&h2s[token * H2_STRIDE + q * 24 + j4 + 2] = (unsigned)b2 | ((unsigned)b3 << 16);
        }
    }
    __syncthreads();

    {
        f32x4 acc[6][4];
#pragma unroll
        for (int mi = 0; mi < 6; mi++) {
            const float4 bv = *(const float4*)&bf1[(wave * 6 + mi) * 16 + lk * 4];
            f32x4 bi = {bv.x, bv.y, bv.z, bv.w};
#pragma unroll
            for (int n4 = 0; n4 < 4; n4++) acc[mi][n4] = bi;
        }
#pragma unroll
        for (int kt = 0; kt < 3; kt++) {
            bf16x8 bfrag[4];
#pragma unroll
            for (int n4 = 0; n4 < 4; n4++)
                bfrag[n4] = *(const bf16x8*)&h2s[(n4 * 16 + lm) * H2_STRIDE + kt * 32 + lk * 8];
            bf16x8 afrag[6];
#pragma unroll
            for (int mi = 0; mi < 6; mi++)
                afrag[mi] = *(const bf16x8*)&w1t[((wave * 6 + mi) * 16 + lm) * 96 + kt * 32 + lk * 8];
#pragma unroll
            for (int mi = 0; mi < 6; mi++)
#pragma unroll
                for (int n4 = 0; n4 < 4; n4++)
                    acc[mi][n4] = __builtin_amdgcn_mfma_f32_16x16x32_bf16(
                        afrag[mi], bfrag[n4], acc[mi][n4], 0, 0, 0);
        }
#pragma unroll
        for (int mi = 0; mi < 6; mi++) {
            const int h0 = (wave * 6 + mi) * 16 + lk * 4;
#pragma unroll
            for (int n4 = 0; n4 < 4; n4++) {
                const int t = n4 * 16 + lm;
                ushort4 pk;
#pragma unroll
                for (int r = 0; r < 4; r++) {
                    float vv = acc[mi][n4][r];
                    float gl = 0.5f * vv * (1.0f + erff(vv * 0.70710678118654752f));
                    ((unsigned short*)&pk)[r] = f2bf(gl);
                }
                *(ushort4*)&mss[t * MS_STRIDE + h0] = pk;
            }
        }
    }
    __syncthreads();

    {
        f32x4 acc2[6];
#pragma unroll
        for (int nt = 0; nt < 6; nt++) {
            float bb = bf2v[nt * 16 + lm];
            acc2[nt] = {bb, bb, bb, bb};
        }
#pragma unroll 4
        for (int kt = 0; kt < 12; kt++) {
            bf16x8 a = *(const bf16x8*)&mss[(wave * 16 + lm) * MS_STRIDE + kt * 32 + lk * 8];
#pragma unroll
            for (int nt = 0; nt < 6; nt++) {
                bf16x8 bb = *(const bf16x8*)&w2t[(nt * 16 + lm) * 384 + kt * 32 + lk * 8];
                acc2[nt] = __builtin_amdgcn_mfma_f32_16x16x32_bf16(a, bb, acc2[nt], 0, 0, 0);
            }
        }
#pragma unroll
        for (int nt = 0; nt < 6; nt++) {
            const int c = nt * 16 + lm;
#pragma unroll
            for (int r = 0; r < 4; r++) {
                const int t = wave * 16 + lk * 4 + r;
                size_t gi = (t0 + t) * 96 + c;
                y[gi] = y[gi] + acc2[nt][r];
            }
        }
    }
}

// ---------------- launcher ----------------
extern "C" void kernel_launch(void* const* d_in, const int* in_sizes, int n_in,
                              void* d_out, int out_size, void* d_ws, size_t ws_size,
                              hipStream_t stream) {
    const float* x      = (const float*)d_in[0];
    const float* w_qkv  = (const float*)d_in[1];
    const float* b_qkv  = (const float*)d_in[2];
    const float* w_proj = (const float*)d_in[3];
    const float* b_proj = (const float*)d_in[4];
    const float* rpb    = (const float*)d_in[5];
    const float* g1     = (const float*)d_in[6];
    const float* be1    = (const float*)d_in[7];
    const float* g2     = (const float*)d_in[8];
    const float* be2    = (const float*)d_in[9];
    const float* wf1    = (const float*)d_in[10];
    const float* bf1    = (const float*)d_in[11];
    const float* wf2    = (const float*)d_in[12];
    const float* bf2v   = (const float*)d_in[13];
    float* out = (float*)d_out;

    // workspace layout (bf16 weights + scaled qkv bias)
    unsigned short* w1t    = (unsigned short*)d_ws;
    unsigned short* w2t    = w1t + 384 * 96;
    unsigned short* wqkvT  = w2t + 384 * 96;
    unsigned short* wprojT = wqkvT + 288 * 96;
    float*          bqkv   = (float*)(wprojT + 96 * 96);

    prep_weights<<<144, 256, 0, stream>>>(wf1, wf2, w_qkv, b_qkv, w_proj,
                                          w1t, w2t, wqkvT, wprojT, bqkv);

    const int nwin_total = BATCH * NWIN * NWIN;          // 16384
    attn_mfma_kernel<<<nwin_total, 256, 0, stream>>>(x, rpb, g1, be1, b_proj,
                                                     wqkvT, wprojT, bqkv, out);

    const int ntok_blocks = (BATCH * LTOK) / MTOK;       // 12544
    mlp_mfma_kernel<<<ntok_blocks, 256, 0, stream>>>(out, g2, be2, bf1, bf2v, w1t, w2t);
}